// Round 1
// 1311.018 us; speedup vs baseline: 1.0763x; 1.0763x over previous
//
#include <hip/hip_runtime.h>
#include <hip/hip_bf16.h>

typedef __bf16 bf8_t __attribute__((ext_vector_type(8)));
typedef float  f32x4 __attribute__((ext_vector_type(4)));

constexpr int N_NODES = 100000;
constexpr int E_ORIG  = 600000;
constexpr int E_LINE  = 1200000;

static inline int cdiv(int a, int b) { return (a + b - 1) / b; }

enum { A_DENSE = 0, A_AGG = 1, A_PAIR = 2 };

// ---- f32 -> bf16 pack (x_orig once) ----
__global__ void k_f2b(const float* __restrict__ X, __bf16* __restrict__ O, int n8) {
    int i = blockIdx.x * 256 + threadIdx.x;
    if (i >= n8) return;
    float4 a = ((const float4*)X)[2 * i], b = ((const float4*)X)[2 * i + 1];
    bf8_t o;
    o[0] = (__bf16)a.x; o[1] = (__bf16)a.y; o[2] = (__bf16)a.z; o[3] = (__bf16)a.w;
    o[4] = (__bf16)b.x; o[5] = (__bf16)b.y; o[6] = (__bf16)b.z; o[7] = (__bf16)b.w;
    ((bf8_t*)O)[i] = o;
}

// ---- CSR build: histogram ----
__global__ void k_hist(const int* __restrict__ dst, int* __restrict__ cnt, int E) {
    int e = blockIdx.x * 256 + threadIdx.x;
    if (e < E) atomicAdd(&cnt[dst[e]], 1);
}

// ---- CSR build: 3-phase exclusive scan over cnt[n] ----
__global__ void k_scan1(const int* __restrict__ cnt, int* __restrict__ offs,
                        int* __restrict__ bsum, int n) {
    __shared__ int tmp[256];
    int i = blockIdx.x * 256 + threadIdx.x;
    int v = (i < n) ? cnt[i] : 0;
    tmp[threadIdx.x] = v; __syncthreads();
    #pragma unroll
    for (int d = 1; d < 256; d <<= 1) {
        int t = (threadIdx.x >= d) ? tmp[threadIdx.x - d] : 0;
        __syncthreads();
        tmp[threadIdx.x] += t;
        __syncthreads();
    }
    if (i < n) offs[i] = tmp[threadIdx.x] - v;      // exclusive within block
    if (threadIdx.x == 255) bsum[blockIdx.x] = tmp[255];
}

__global__ void k_scan2(int* __restrict__ bsum, int nb) {
    __shared__ int tmp[256];
    __shared__ int carry;
    if (threadIdx.x == 0) carry = 0;
    __syncthreads();
    for (int base = 0; base < nb; base += 256) {
        int i = base + threadIdx.x;
        int v = (i < nb) ? bsum[i] : 0;
        tmp[threadIdx.x] = v; __syncthreads();
        #pragma unroll
        for (int d = 1; d < 256; d <<= 1) {
            int t = (threadIdx.x >= d) ? tmp[threadIdx.x - d] : 0;
            __syncthreads();
            tmp[threadIdx.x] += t;
            __syncthreads();
        }
        int tot = tmp[255];
        if (i < nb) bsum[i] = tmp[threadIdx.x] - v + carry;
        __syncthreads();
        if (threadIdx.x == 0) carry += tot;
        __syncthreads();
    }
}

__global__ void k_scan3(int* __restrict__ offs, int* __restrict__ cur,
                        const int* __restrict__ bsum, int n) {
    int i = blockIdx.x * 256 + threadIdx.x;
    if (i >= n) return;
    int o = offs[i] + bsum[blockIdx.x];
    offs[i] = o;
    cur[i]  = o;
}

// ---- CSR build: bucket fill ----
__global__ void k_fill(const int* __restrict__ src, const int* __restrict__ dst,
                       int* __restrict__ cur, int* __restrict__ adj, int E) {
    int e = blockIdx.x * 256 + threadIdx.x;
    if (e >= E) return;
    int p = atomicAdd(&cur[dst[e]], 1);
    adj[p] = src[e];
}

// ---- one-time weight pre-pack: f32 [128][128] -> bf16 fragment-major ----
// frag(c,s): lane l, elem j  <- W[k = s*32 + (l>>4)*8 + j][n = c*16 + (l&15)]
struct WPtrs { const float* p[10]; };

__global__ void k_packW(WPtrs wp, __bf16* __restrict__ out) {
    const float* W = wp.p[blockIdx.x];
    __bf16* O = out + (size_t)blockIdx.x * 16384;
    const float4* W4 = (const float4*)W;
    for (int e = threadIdx.x; e < 4096; e += 256) {
        float4 w = W4[e];
        unsigned flat = (unsigned)e * 4;
        unsigned k = flat >> 7, n = flat & 127;
        unsigned c = n >> 4, s = k >> 5, hi = (k >> 3) & 3, j = k & 7;
        unsigned l0 = (hi << 4) | (n & 15);
        unsigned base = ((c * 4 + s) * 64 + l0) * 8 + j;
        O[base]      = (__bf16)w.x;
        O[base + 8]  = (__bf16)w.y;
        O[base + 16] = (__bf16)w.z;
        O[base + 24] = (__bf16)w.w;
    }
}

// ---- fused GIN layer: out = act2(act1(bn((x+agg(x)) @ W1 + b1)) @ W2 + b2) ----
// MODE: A_DENSE  stage1 A = X rows (no gather)
//       A_AGG    A[r] = X[r] + sum_{j in adj} X[j]
//       A_PAIR   A[r] = h(r) + sum_{j in adj} h(j), h(x) = X[p0[x]] + X[p1[x]]
// 128 rows / block, 4 waves x 32 rows, A/H share one swizzled 32KB LDS tile.
template<int MODE, bool RELU2>
__launch_bounds__(256, 2)
__global__ void k_layer(const __bf16* __restrict__ X, int M,
                        const int* __restrict__ offs, const int* __restrict__ cnt,
                        const int* __restrict__ adj, const int* __restrict__ pairs,
                        const __bf16* __restrict__ Wp1, const __bf16* __restrict__ Wp2,
                        const float* __restrict__ b1,
                        const float* __restrict__ bg, const float* __restrict__ bb,
                        const float* __restrict__ bm, const float* __restrict__ bv,
                        const float* __restrict__ b2,
                        __bf16* __restrict__ out) {
    __shared__ __bf16 sA[128 * 128];   // gathered A, then H (chunk ^ (row&7) swizzle)
    __shared__ __bf16 sW[128 * 128];   // W1, then W2 (pre-packed fragment-major)
    __shared__ float sS1[128], sT1[128], sT2[128];

    const int tid = threadIdx.x;
    const int rowBase = blockIdx.x * 128;

    // prefetch W1 (32 KB, issued before the gather so latency hides under it)
    bf8_t w1r[8];
    #pragma unroll
    for (int i = 0; i < 8; ++i) w1r[i] = ((const bf8_t*)Wp1)[i * 256 + tid];

    // fold BN + bias into per-column scale/shift: h1 = dot*S1 + T1 ; h2 = dot + T2
    if (tid < 128) {
        float b = b1[tid];
        float g = bg[tid], be = bb[tid], m = bm[tid], v = bv[tid];
        float S = g * rsqrtf(v + 1e-5f);
        sS1[tid] = S;
        sT1[tid] = b * S + (be - m * S);
        sT2[tid] = b2[tid];
    }

    // ---- gather-aggregate phase (quarter-wave per row, 8 passes of 16 rows) ----
    if (MODE != A_DENSE) {
        const int c  = tid & 15;       // 16B chunk of the row
        const int r0 = tid >> 4;
        for (int p = 0; p < 8; ++p) {
            int rl = p * 16 + r0;
            int grow = rowBase + rl;
            float acc[8];
            if (grow < M) {
                int s = offs[grow], n = cnt[grow];
                if (MODE == A_AGG) {
                    bf8_t self = *((const bf8_t*)(X + (size_t)grow * 128) + c);
                    #pragma unroll
                    for (int j = 0; j < 8; ++j) acc[j] = (float)self[j];
                    int k = 0;
                    for (; k + 2 <= n; k += 2) {            // 2 neighbors in flight
                        int a0 = adj[s + k], a1 = adj[s + k + 1];
                        bf8_t v0 = *((const bf8_t*)(X + (size_t)a0 * 128) + c);
                        bf8_t v1 = *((const bf8_t*)(X + (size_t)a1 * 128) + c);
                        #pragma unroll
                        for (int j = 0; j < 8; ++j) acc[j] += (float)v0[j];
                        #pragma unroll
                        for (int j = 0; j < 8; ++j) acc[j] += (float)v1[j];
                    }
                    if (k < n) {
                        int a0 = adj[s + k];
                        bf8_t v0 = *((const bf8_t*)(X + (size_t)a0 * 128) + c);
                        #pragma unroll
                        for (int j = 0; j < 8; ++j) acc[j] += (float)v0[j];
                    }
                } else {                                    // A_PAIR
                    int2 pr = ((const int2*)pairs)[grow];
                    bf8_t v0 = *((const bf8_t*)(X + (size_t)pr.x * 128) + c);
                    bf8_t v1 = *((const bf8_t*)(X + (size_t)pr.y * 128) + c);
                    #pragma unroll
                    for (int j = 0; j < 8; ++j) acc[j] = (float)v0[j] + (float)v1[j];
                    int k = 0;
                    for (; k + 2 <= n; k += 2) {
                        int a0 = adj[s + k], a1 = adj[s + k + 1];
                        int2 q0 = ((const int2*)pairs)[a0];
                        int2 q1 = ((const int2*)pairs)[a1];
                        bf8_t u0 = *((const bf8_t*)(X + (size_t)q0.x * 128) + c);
                        bf8_t u1 = *((const bf8_t*)(X + (size_t)q0.y * 128) + c);
                        bf8_t u2 = *((const bf8_t*)(X + (size_t)q1.x * 128) + c);
                        bf8_t u3 = *((const bf8_t*)(X + (size_t)q1.y * 128) + c);
                        #pragma unroll
                        for (int j = 0; j < 8; ++j)
                            acc[j] += (float)u0[j] + (float)u1[j] + (float)u2[j] + (float)u3[j];
                    }
                    if (k < n) {
                        int a0 = adj[s + k];
                        int2 q0 = ((const int2*)pairs)[a0];
                        bf8_t u0 = *((const bf8_t*)(X + (size_t)q0.x * 128) + c);
                        bf8_t u1 = *((const bf8_t*)(X + (size_t)q0.y * 128) + c);
                        #pragma unroll
                        for (int j = 0; j < 8; ++j) acc[j] += (float)u0[j] + (float)u1[j];
                    }
                }
            } else {
                #pragma unroll
                for (int j = 0; j < 8; ++j) acc[j] = 0.f;
            }
            bf8_t o;
            #pragma unroll
            for (int j = 0; j < 8; ++j) o[j] = (__bf16)acc[j];
            *(bf8_t*)&sA[rl * 128 + ((c ^ (rl & 7)) << 3)] = o;   // swizzled store
        }
    }

    // ---- commit W1 to LDS (loads long done), then sync ----
    #pragma unroll
    for (int i = 0; i < 8; ++i) ((bf8_t*)sW)[i * 256 + tid] = w1r[i];
    __syncthreads();

    // prefetch W2 while stage-1 MFMAs run
    bf8_t w2r[8];
    #pragma unroll
    for (int i = 0; i < 8; ++i) w2r[i] = ((const bf8_t*)Wp2)[i * 256 + tid];

    const int lane = tid & 63;
    const int wv   = tid >> 6;            // wave owns rows [wv*32, wv*32+32)
    const int m0 = lane & 15, kq = lane >> 4;

    // ---- stage 1: A @ W1 ----
    f32x4 acc[2][8];
    #pragma unroll
    for (int rt = 0; rt < 2; ++rt)
        #pragma unroll
        for (int ct = 0; ct < 8; ++ct) acc[rt][ct] = (f32x4){0.f, 0.f, 0.f, 0.f};

    #pragma unroll
    for (int s = 0; s < 4; ++s) {
        bf8_t fa[2];
        #pragma unroll
        for (int rt = 0; rt < 2; ++rt) {
            int rl = wv * 32 + rt * 16 + m0;
            if (MODE == A_DENSE) {
                int r = rowBase + rl;
                r = r < M ? r : M - 1;                 // clamp; tail rows never stored
                fa[rt] = *(const bf8_t*)(X + (size_t)r * 128 + s * 32 + kq * 8);
            } else {
                int chunk = s * 4 + kq;
                fa[rt] = *(const bf8_t*)&sA[rl * 128 + ((chunk ^ (rl & 7)) << 3)];
            }
        }
        #pragma unroll
        for (int ct = 0; ct < 8; ++ct) {
            bf8_t fw = *(const bf8_t*)&sW[((ct * 4 + s) * 64 + lane) * 8];
            #pragma unroll
            for (int rt = 0; rt < 2; ++rt)
                acc[rt][ct] = __builtin_amdgcn_mfma_f32_16x16x32_bf16(fa[rt], fw, acc[rt][ct], 0, 0, 0);
        }
    }

    // ---- epilogue 1: BN+ReLU, H -> sA (wave-local slab; in-order DS makes RAW safe) ----
    // C/D layout: col = lane&15, row = (lane>>4)*4 + reg   [m89]
    #pragma unroll
    for (int rt = 0; rt < 2; ++rt) {
        #pragma unroll
        for (int r = 0; r < 4; ++r) {
            int rl = wv * 32 + rt * 16 + kq * 4 + r;
            #pragma unroll
            for (int ct = 0; ct < 8; ++ct) {
                int col = ct * 16 + m0;
                float v = acc[rt][ct][r] * sS1[col] + sT1[col];
                v = fmaxf(v, 0.f);
                int chunk = col >> 3;
                sA[rl * 128 + ((chunk ^ (rl & 7)) << 3) + (col & 7)] = (__bf16)v;
            }
        }
    }
    __syncthreads();                       // all waves done reading sW (stage 1)

    // ---- swap W2 into LDS ----
    #pragma unroll
    for (int i = 0; i < 8; ++i) ((bf8_t*)sW)[i * 256 + tid] = w2r[i];
    __syncthreads();

    // ---- stage 2: H @ W2 ----
    f32x4 acc2[2][8];
    #pragma unroll
    for (int rt = 0; rt < 2; ++rt)
        #pragma unroll
        for (int ct = 0; ct < 8; ++ct) acc2[rt][ct] = (f32x4){0.f, 0.f, 0.f, 0.f};

    #pragma unroll
    for (int s = 0; s < 4; ++s) {
        bf8_t fa[2];
        #pragma unroll
        for (int rt = 0; rt < 2; ++rt) {
            int rl = wv * 32 + rt * 16 + m0;
            int chunk = s * 4 + kq;
            fa[rt] = *(const bf8_t*)&sA[rl * 128 + ((chunk ^ (rl & 7)) << 3)];
        }
        #pragma unroll
        for (int ct = 0; ct < 8; ++ct) {
            bf8_t fw = *(const bf8_t*)&sW[((ct * 4 + s) * 64 + lane) * 8];
            #pragma unroll
            for (int rt = 0; rt < 2; ++rt)
                acc2[rt][ct] = __builtin_amdgcn_mfma_f32_16x16x32_bf16(fa[rt], fw, acc2[rt][ct], 0, 0, 0);
        }
    }

    // ---- epilogue 2: + b2 (+ReLU), store bf16 ----
    #pragma unroll
    for (int rt = 0; rt < 2; ++rt) {
        #pragma unroll
        for (int r = 0; r < 4; ++r) {
            int row = rowBase + wv * 32 + rt * 16 + kq * 4 + r;
            if (row < M) {
                #pragma unroll
                for (int ct = 0; ct < 8; ++ct) {
                    int col = ct * 16 + m0;
                    float v = acc2[rt][ct][r] + sT2[col];
                    if (RELU2) v = fmaxf(v, 0.f);
                    out[(size_t)row * 128 + col] = (__bf16)v;
                }
            }
        }
    }
}

// ---- plain fused GEMM (kept for the 128->64 output projection) ----
template<int NC, bool BN, bool RELU, bool OUTF32>
__launch_bounds__(256, 2)
__global__ void k_gemm(const __bf16* __restrict__ A, int M,
                       const float* __restrict__ W,
                       const float* __restrict__ bias,
                       const float* __restrict__ bg, const float* __restrict__ bb,
                       const float* __restrict__ bm, const float* __restrict__ bv,
                       void* __restrict__ outp) {
    constexpr int NT = NC / 16;
    __shared__ __bf16 sW[128 * NC];
    __shared__ float sS[NC];
    __shared__ float sT[NC];

    const float4* W4 = (const float4*)W;
    for (int e = threadIdx.x; e < 32 * NC; e += 256) {
        float4 w = W4[e];
        unsigned flat = (unsigned)e * 4;
        unsigned k = flat / NC, n = flat % NC;
        unsigned c = n >> 4, s = k >> 5, hi = (k >> 3) & 3, j = k & 7;
        unsigned l0 = (hi << 4) | (n & 15);
        unsigned base = ((c * 4 + s) * 64 + l0) * 8 + j;
        sW[base]      = (__bf16)w.x;
        sW[base + 8]  = (__bf16)w.y;
        sW[base + 16] = (__bf16)w.z;
        sW[base + 24] = (__bf16)w.w;
    }
    for (int n = threadIdx.x; n < NC; n += 256) {
        float b = bias[n];
        float S = 1.0f, T = b;
        if (BN) {
            float g = bg[n], be = bb[n], m = bm[n], v = bv[n];
            S = g * rsqrtf(v + 1e-5f);
            T = b * S + (be - m * S);
        }
        sS[n] = S; sT[n] = T;
    }
    __syncthreads();

    const int lane = threadIdx.x & 63;
    const int wv   = threadIdx.x >> 6;
    const int rowBase = blockIdx.x * 256 + wv * 64;
    const int m0 = lane & 15, kq = lane >> 4;

    f32x4 acc[4][NT];
    #pragma unroll
    for (int rt = 0; rt < 4; ++rt)
        #pragma unroll
        for (int ct = 0; ct < NT; ++ct)
            acc[rt][ct] = (f32x4){0.f, 0.f, 0.f, 0.f};

    #pragma unroll
    for (int s = 0; s < 4; ++s) {
        bf8_t fa[4];
        #pragma unroll
        for (int rt = 0; rt < 4; ++rt) {
            int r = rowBase + rt * 16 + m0;
            r = r < M ? r : M - 1;
            fa[rt] = *(const bf8_t*)(A + (size_t)r * 128 + s * 32 + kq * 8);
        }
        #pragma unroll
        for (int ct = 0; ct < NT; ++ct) {
            bf8_t fw = *(const bf8_t*)&sW[((ct * 4 + s) * 64 + lane) * 8];
            #pragma unroll
            for (int rt = 0; rt < 4; ++rt)
                acc[rt][ct] = __builtin_amdgcn_mfma_f32_16x16x32_bf16(fa[rt], fw, acc[rt][ct], 0, 0, 0);
        }
    }

    #pragma unroll
    for (int rt = 0; rt < 4; ++rt) {
        #pragma unroll
        for (int r = 0; r < 4; ++r) {
            int row = rowBase + rt * 16 + kq * 4 + r;
            if (row < M) {
                #pragma unroll
                for (int ct = 0; ct < NT; ++ct) {
                    int col = ct * 16 + m0;
                    float v = acc[rt][ct][r] * sS[col] + sT[col];
                    if (RELU) v = fmaxf(v, 0.0f);
                    size_t o = (size_t)row * NC + col;
                    if constexpr (OUTF32) ((float*)outp)[o]  = v;
                    else                  ((__bf16*)outp)[o] = (__bf16)v;
                }
            }
        }
    }
}

extern "C" void kernel_launch(void* const* d_in, const int* in_sizes, int n_in,
                              void* d_out, int out_size, void* d_ws, size_t ws_size,
                              hipStream_t stream) {
    const int*   edge_index = (const int*)d_in[0];     // [2, E_LINE]
    const float* x_orig     = (const float*)d_in[1];   // [N_NODES, 128] f32
    const int*   eio        = (const int*)d_in[2];     // [2, E_ORIG]
    const int*   pairs      = (const int*)d_in[3];     // [E_ORIG, 2]
    const float* iW1 = (const float*)d_in[4];
    const float* ib1 = (const float*)d_in[5];
    const float* ig  = (const float*)d_in[6];
    const float* ibb = (const float*)d_in[7];
    const float* im  = (const float*)d_in[8];
    const float* iv  = (const float*)d_in[9];
    const float* iW2 = (const float*)d_in[10];
    const float* ib2 = (const float*)d_in[11];
    const float* gW1 = (const float*)d_in[12];
    const float* gb1 = (const float*)d_in[13];
    const float* gg  = (const float*)d_in[14];
    const float* gbb = (const float*)d_in[15];
    const float* gm  = (const float*)d_in[16];
    const float* gv  = (const float*)d_in[17];
    const float* gW2 = (const float*)d_in[18];
    const float* gb2 = (const float*)d_in[19];
    const float* mW1 = (const float*)d_in[20];
    const float* mb1 = (const float*)d_in[21];
    const float* mg  = (const float*)d_in[22];
    const float* mbb = (const float*)d_in[23];
    const float* mm  = (const float*)d_in[24];
    const float* mv  = (const float*)d_in[25];
    const float* mW2 = (const float*)d_in[26];
    const float* mb2 = (const float*)d_in[27];
    const float* oW  = (const float*)d_in[28];
    const float* ob  = (const float*)d_in[29];

    // ---- workspace carve ----
    char* w = (char*)d_ws;
    __bf16* EB  = (__bf16*)w;                w += (size_t)E_ORIG * 128 * 2;   // 153.6 MB
    __bf16* XB  = (__bf16*)w;                w += (size_t)N_NODES * 128 * 2;  // 25.6 MB
    __bf16* NA  = (__bf16*)w;                w += (size_t)N_NODES * 128 * 2;  // 25.6 MB
    __bf16* NB  = (__bf16*)w;                w += (size_t)N_NODES * 128 * 2;  // 25.6 MB
    int* cnt  = (int*)w;                     w += (size_t)E_ORIG * 4;         // 2.4 MB
    int* offs = (int*)w;                     w += (size_t)E_ORIG * 4;         // 2.4 MB
    int* cur  = (int*)w;                     w += (size_t)E_ORIG * 4;         // 2.4 MB
    int* bsum = (int*)w;                     w += 4096 * 4;
    int* adj  = (int*)w;                     w += (size_t)E_LINE * 4;         // 4.8 MB
    __bf16* Wpk = (__bf16*)w;                /* 10 * 16384 bf16 = 320 KB */
    __bf16* EBd = (__bf16*)d_out;            // d_out doubles as edge scratch (bf16)

    const int* eio_src = eio;
    const int* eio_dst = eio + E_ORIG;
    const int* el_src  = edge_index;
    const int* el_dst  = edge_index + E_LINE;

    const int nBlk = cdiv(N_NODES, 128);       // 782
    const int eBlk = cdiv(E_ORIG, 128);        // 4688
    const int nScanNB = cdiv(N_NODES, 256);    // 391
    const int eScanNB = cdiv(E_ORIG, 256);     // 2344

    // ---- pre-pack all 128x128 weights to bf16 fragment-major (once per launch) ----
    WPtrs wp;
    wp.p[0] = iW1;          wp.p[1] = iW2;
    wp.p[2] = iW1 + 16384;  wp.p[3] = iW2 + 16384;
    wp.p[4] = mW1;          wp.p[5] = mW2;
    wp.p[6] = gW1;          wp.p[7] = gW2;
    wp.p[8] = gW1 + 16384;  wp.p[9] = gW2 + 16384;
    k_packW<<<10, 256, 0, stream>>>(wp, Wpk);

    // ==== node-graph CSR (dst = eio_dst, n = N_NODES, E = E_ORIG) ====
    hipMemsetAsync(cnt, 0, (size_t)N_NODES * 4, stream);
    k_hist <<<cdiv(E_ORIG, 256), 256, 0, stream>>>(eio_dst, cnt, E_ORIG);
    k_scan1<<<nScanNB, 256, 0, stream>>>(cnt, offs, bsum, N_NODES);
    k_scan2<<<1, 256, 0, stream>>>(bsum, nScanNB);
    k_scan3<<<nScanNB, 256, 0, stream>>>(offs, cur, bsum, N_NODES);
    k_fill <<<cdiv(E_ORIG, 256), 256, 0, stream>>>(eio_src, eio_dst, cur, adj, E_ORIG);

    // ==== node stage ====
    k_f2b<<<cdiv(N_NODES * 16, 256), 256, 0, stream>>>(x_orig, XB, N_NODES * 16);
    // init GIN layer 0 (fused agg + W1 + BN + ReLU + W2 + ReLU)
    k_layer<A_AGG, true><<<nBlk, 256, 0, stream>>>(XB, N_NODES, offs, cnt, adj, nullptr,
        Wpk + 0 * 16384, Wpk + 1 * 16384, ib1, ig, ibb, im, iv, ib2, NA);
    // init GIN layer 1
    k_layer<A_AGG, true><<<nBlk, 256, 0, stream>>>(NA, N_NODES, offs, cnt, adj, nullptr,
        Wpk + 2 * 16384, Wpk + 3 * 16384, ib1 + 128, ig + 128, ibb + 128, im + 128, iv + 128, ib2 + 128, NB);
    // per-node MLP (dense fused pair; plain second layer)
    k_layer<A_DENSE, false><<<nBlk, 256, 0, stream>>>(NB, N_NODES, nullptr, nullptr, nullptr, nullptr,
        Wpk + 4 * 16384, Wpk + 5 * 16384, mb1, mg, mbb, mm, mv, mb2, XB);

    // ==== line-graph CSR (dst = el_dst, n = E_ORIG, E = E_LINE) ====
    hipMemsetAsync(cnt, 0, (size_t)E_ORIG * 4, stream);
    k_hist <<<cdiv(E_LINE, 256), 256, 0, stream>>>(el_dst, cnt, E_LINE);
    k_scan1<<<eScanNB, 256, 0, stream>>>(cnt, offs, bsum, E_ORIG);
    k_scan2<<<1, 256, 0, stream>>>(bsum, eScanNB);
    k_scan3<<<eScanNB, 256, 0, stream>>>(offs, cur, bsum, E_ORIG);
    k_fill <<<cdiv(E_LINE, 256), 256, 0, stream>>>(el_src, el_dst, cur, adj, E_LINE);

    // ==== edge stage ====
    // GIN layer 0: pair-gather + agg + both GEMMs fused (EB / h never materialized)
    k_layer<A_PAIR, true><<<eBlk, 256, 0, stream>>>(XB, E_ORIG, offs, cnt, adj, pairs,
        Wpk + 6 * 16384, Wpk + 7 * 16384, gb1, gg, gbb, gm, gv, gb2, EBd);
    // GIN layer 1
    k_layer<A_AGG, true><<<eBlk, 256, 0, stream>>>(EBd, E_ORIG, offs, cnt, adj, nullptr,
        Wpk + 8 * 16384, Wpk + 9 * 16384, gb1 + 128, gg + 128, gbb + 128, gm + 128, gv + 128, gb2 + 128, EB);

    // ==== output projection: [E_ORIG,128]bf16 @ [128,64] + b -> d_out f32 ====
    k_gemm<64, false, false, true><<<cdiv(E_ORIG, 256), 256, 0, stream>>>(EB, E_ORIG, oW, ob,
        nullptr, nullptr, nullptr, nullptr, d_out);
}

// Round 2
// 1082.094 us; speedup vs baseline: 1.3040x; 1.2116x over previous
//
#include <hip/hip_runtime.h>
#include <hip/hip_bf16.h>

typedef __bf16 bf8_t __attribute__((ext_vector_type(8)));
typedef float  f32x4 __attribute__((ext_vector_type(4)));

constexpr int N_NODES = 100000;
constexpr int E_ORIG  = 600000;
constexpr int E_LINE  = 1200000;

static inline int cdiv(int a, int b) { return (a + b - 1) / b; }

enum { A_DENSE = 0, A_AGG = 1, A_PAIR = 2 };

// ---- f32 -> bf16 pack (x_orig once) ----
__global__ void k_f2b(const float* __restrict__ X, __bf16* __restrict__ O, int n8) {
    int i = blockIdx.x * 256 + threadIdx.x;
    if (i >= n8) return;
    float4 a = ((const float4*)X)[2 * i], b = ((const float4*)X)[2 * i + 1];
    bf8_t o;
    o[0] = (__bf16)a.x; o[1] = (__bf16)a.y; o[2] = (__bf16)a.z; o[3] = (__bf16)a.w;
    o[4] = (__bf16)b.x; o[5] = (__bf16)b.y; o[6] = (__bf16)b.z; o[7] = (__bf16)b.w;
    ((bf8_t*)O)[i] = o;
}

// ---- CSR build: histogram ----
__global__ void k_hist(const int* __restrict__ dst, int* __restrict__ cnt, int E) {
    int e = blockIdx.x * 256 + threadIdx.x;
    if (e < E) atomicAdd(&cnt[dst[e]], 1);
}

// ---- CSR build: 3-phase exclusive scan over cnt[n] ----
__global__ void k_scan1(const int* __restrict__ cnt, int* __restrict__ offs,
                        int* __restrict__ bsum, int n) {
    __shared__ int tmp[256];
    int i = blockIdx.x * 256 + threadIdx.x;
    int v = (i < n) ? cnt[i] : 0;
    tmp[threadIdx.x] = v; __syncthreads();
    #pragma unroll
    for (int d = 1; d < 256; d <<= 1) {
        int t = (threadIdx.x >= d) ? tmp[threadIdx.x - d] : 0;
        __syncthreads();
        tmp[threadIdx.x] += t;
        __syncthreads();
    }
    if (i < n) offs[i] = tmp[threadIdx.x] - v;      // exclusive within block
    if (threadIdx.x == 255) bsum[blockIdx.x] = tmp[255];
}

__global__ void k_scan2(int* __restrict__ bsum, int nb) {
    __shared__ int tmp[256];
    __shared__ int carry;
    if (threadIdx.x == 0) carry = 0;
    __syncthreads();
    for (int base = 0; base < nb; base += 256) {
        int i = base + threadIdx.x;
        int v = (i < nb) ? bsum[i] : 0;
        tmp[threadIdx.x] = v; __syncthreads();
        #pragma unroll
        for (int d = 1; d < 256; d <<= 1) {
            int t = (threadIdx.x >= d) ? tmp[threadIdx.x - d] : 0;
            __syncthreads();
            tmp[threadIdx.x] += t;
            __syncthreads();
        }
        int tot = tmp[255];
        if (i < nb) bsum[i] = tmp[threadIdx.x] - v + carry;
        __syncthreads();
        if (threadIdx.x == 0) carry += tot;
        __syncthreads();
    }
}

__global__ void k_scan3(int* __restrict__ offs, int* __restrict__ cur,
                        const int* __restrict__ bsum, int n) {
    int i = blockIdx.x * 256 + threadIdx.x;
    if (i >= n) return;
    int o = offs[i] + bsum[blockIdx.x];
    offs[i] = o;
    cur[i]  = o;
}

// ---- CSR build: bucket fill ----
__global__ void k_fill(const int* __restrict__ src, const int* __restrict__ dst,
                       int* __restrict__ cur, int* __restrict__ adj, int E) {
    int e = blockIdx.x * 256 + threadIdx.x;
    if (e >= E) return;
    int p = atomicAdd(&cur[dst[e]], 1);
    adj[p] = src[e];
}

// ---- one-time weight pre-pack: f32 [128][128] -> bf16 fragment-major ----
// frag(c,s): lane l, elem j  <- W[k = s*32 + (l>>4)*8 + j][n = c*16 + (l&15)]
struct WPtrs { const float* p[10]; };

__global__ void k_packW(WPtrs wp, __bf16* __restrict__ out) {
    const float* W = wp.p[blockIdx.x];
    __bf16* O = out + (size_t)blockIdx.x * 16384;
    const float4* W4 = (const float4*)W;
    for (int e = threadIdx.x; e < 4096; e += 256) {
        float4 w = W4[e];
        unsigned flat = (unsigned)e * 4;
        unsigned k = flat >> 7, n = flat & 127;
        unsigned c = n >> 4, s = k >> 5, hi = (k >> 3) & 3, j = k & 7;
        unsigned l0 = (hi << 4) | (n & 15);
        unsigned base = ((c * 4 + s) * 64 + l0) * 8 + j;
        O[base]      = (__bf16)w.x;
        O[base + 8]  = (__bf16)w.y;
        O[base + 16] = (__bf16)w.z;
        O[base + 24] = (__bf16)w.w;
    }
}

// ---- fused GIN layer: out = act2(act1(bn((x+agg(x)) @ W1 + b1)) @ W2 + b2) ----
// v2: barrier-free. Each wave owns a 32-row slab of sA (gather -> stage1 ->
// H rewrite -> stage2 all same-wave; in-order DS gives RAW safety). W is read
// as B-fragments directly from L2-resident pre-packed Wpk (no sW in LDS).
// LDS = 32 KB -> 4+ blocks/CU; no __syncthreads anywhere.
template<int MODE, bool RELU2>
__launch_bounds__(256, 4)
__global__ void k_layer(const __bf16* __restrict__ X, int M,
                        const int* __restrict__ offs, const int* __restrict__ cnt,
                        const int* __restrict__ adj, const int* __restrict__ pairs,
                        const __bf16* __restrict__ Wp1, const __bf16* __restrict__ Wp2,
                        const float* __restrict__ b1,
                        const float* __restrict__ bg, const float* __restrict__ bb,
                        const float* __restrict__ bm, const float* __restrict__ bv,
                        const float* __restrict__ b2,
                        __bf16* __restrict__ out) {
    __shared__ __bf16 sA[128 * 128];   // gathered A, then H (chunk ^ (row&7) swizzle)

    const int tid  = threadIdx.x;
    const int lane = tid & 63;
    const int wv   = tid >> 6;            // wave owns rows [wv*32, wv*32+32)
    const int rowBase = blockIdx.x * 128;
    const int m0 = lane & 15, kq = lane >> 4;

    // ---- gather-aggregate phase (wave-private 32 rows; deep prefetch) ----
    if (MODE != A_DENSE) {
        const int c    = lane & 15;       // 16B chunk of the row
        const int slot = lane >> 4;       // 4 rows in flight per pass
        int sarr[8], narr[8];
        #pragma unroll
        for (int p = 0; p < 8; ++p) {
            int grow = rowBase + wv * 32 + p * 4 + slot;
            int g = grow < M ? grow : 0;
            sarr[p] = offs[g];
            narr[p] = grow < M ? cnt[g] : 0;
        }
        int pa0[8], pa1[8];               // first two neighbors of each row
        #pragma unroll
        for (int p = 0; p < 8; ++p) {
            pa0[p] = narr[p] > 0 ? adj[sarr[p]]     : 0;
            pa1[p] = narr[p] > 1 ? adj[sarr[p] + 1] : 0;
        }

        if (MODE == A_AGG) {
            #pragma unroll
            for (int half = 0; half < 2; ++half) {
                bf8_t sv[4], n0[4], n1[4];
                #pragma unroll
                for (int q = 0; q < 4; ++q) {
                    int p = half * 4 + q;
                    int grow = rowBase + wv * 32 + p * 4 + slot;
                    int g = grow < M ? grow : 0;
                    sv[q] = *((const bf8_t*)(X + (size_t)g      * 128) + c);
                    n0[q] = *((const bf8_t*)(X + (size_t)pa0[p] * 128) + c);
                    n1[q] = *((const bf8_t*)(X + (size_t)pa1[p] * 128) + c);
                }
                #pragma unroll
                for (int q = 0; q < 4; ++q) {
                    int p = half * 4 + q;
                    int rl = wv * 32 + p * 4 + slot;
                    int n = narr[p];
                    float acc[8];
                    #pragma unroll
                    for (int j = 0; j < 8; ++j) {
                        float a = (float)sv[q][j];
                        if (n > 0) a += (float)n0[q][j];
                        if (n > 1) a += (float)n1[q][j];
                        acc[j] = a;
                    }
                    int s = sarr[p], k = 2;
                    for (; k + 2 <= n; k += 2) {
                        int a0 = adj[s + k], a1 = adj[s + k + 1];
                        bf8_t v0 = *((const bf8_t*)(X + (size_t)a0 * 128) + c);
                        bf8_t v1 = *((const bf8_t*)(X + (size_t)a1 * 128) + c);
                        #pragma unroll
                        for (int j = 0; j < 8; ++j) acc[j] += (float)v0[j] + (float)v1[j];
                    }
                    if (k < n) {
                        int a0 = adj[s + k];
                        bf8_t v0 = *((const bf8_t*)(X + (size_t)a0 * 128) + c);
                        #pragma unroll
                        for (int j = 0; j < 8; ++j) acc[j] += (float)v0[j];
                    }
                    bf8_t o;
                    #pragma unroll
                    for (int j = 0; j < 8; ++j) o[j] = (__bf16)acc[j];
                    *(bf8_t*)&sA[rl * 128 + ((c ^ (rl & 7)) << 3)] = o;
                }
            }
        } else {                          // A_PAIR: h(x) = X[p0[x]] + X[p1[x]]
            #pragma unroll
            for (int half = 0; half < 2; ++half) {
                int2 spr[4], pq0[4], pq1[4];
                #pragma unroll
                for (int q = 0; q < 4; ++q) {
                    int p = half * 4 + q;
                    int grow = rowBase + wv * 32 + p * 4 + slot;
                    int g = grow < M ? grow : 0;
                    spr[q] = ((const int2*)pairs)[g];
                    pq0[q] = ((const int2*)pairs)[pa0[p]];
                    pq1[q] = ((const int2*)pairs)[pa1[p]];
                }
                #pragma unroll
                for (int q = 0; q < 4; ++q) {
                    int p = half * 4 + q;
                    int rl = wv * 32 + p * 4 + slot;
                    int n = narr[p];
                    bf8_t s0 = *((const bf8_t*)(X + (size_t)spr[q].x * 128) + c);
                    bf8_t s1 = *((const bf8_t*)(X + (size_t)spr[q].y * 128) + c);
                    bf8_t u0 = *((const bf8_t*)(X + (size_t)pq0[q].x * 128) + c);
                    bf8_t u1 = *((const bf8_t*)(X + (size_t)pq0[q].y * 128) + c);
                    bf8_t u2 = *((const bf8_t*)(X + (size_t)pq1[q].x * 128) + c);
                    bf8_t u3 = *((const bf8_t*)(X + (size_t)pq1[q].y * 128) + c);
                    float acc[8];
                    #pragma unroll
                    for (int j = 0; j < 8; ++j) {
                        float a = (float)s0[j] + (float)s1[j];
                        if (n > 0) a += (float)u0[j] + (float)u1[j];
                        if (n > 1) a += (float)u2[j] + (float)u3[j];
                        acc[j] = a;
                    }
                    int s = sarr[p];
                    for (int k = 2; k < n; ++k) {
                        int a0 = adj[s + k];
                        int2 qq = ((const int2*)pairs)[a0];
                        bf8_t w0 = *((const bf8_t*)(X + (size_t)qq.x * 128) + c);
                        bf8_t w1 = *((const bf8_t*)(X + (size_t)qq.y * 128) + c);
                        #pragma unroll
                        for (int j = 0; j < 8; ++j) acc[j] += (float)w0[j] + (float)w1[j];
                    }
                    bf8_t o;
                    #pragma unroll
                    for (int j = 0; j < 8; ++j) o[j] = (__bf16)acc[j];
                    *(bf8_t*)&sA[rl * 128 + ((c ^ (rl & 7)) << 3)] = o;
                }
            }
        }
    }

    // ---- stage 1: A @ W1  (B fragments straight from L2-resident Wpk) ----
    f32x4 acc[2][8];
    #pragma unroll
    for (int rt = 0; rt < 2; ++rt)
        #pragma unroll
        for (int ct = 0; ct < 8; ++ct) acc[rt][ct] = (f32x4){0.f, 0.f, 0.f, 0.f};

    #pragma unroll
    for (int s = 0; s < 4; ++s) {
        bf8_t fa[2];
        #pragma unroll
        for (int rt = 0; rt < 2; ++rt) {
            int rl = wv * 32 + rt * 16 + m0;
            if (MODE == A_DENSE) {
                int r = rowBase + rl;
                r = r < M ? r : M - 1;                 // clamp; tail rows never stored
                fa[rt] = *(const bf8_t*)(X + (size_t)r * 128 + s * 32 + kq * 8);
            } else {
                int chunk = s * 4 + kq;
                fa[rt] = *(const bf8_t*)&sA[rl * 128 + ((chunk ^ (rl & 7)) << 3)];
            }
        }
        #pragma unroll
        for (int ct = 0; ct < 8; ++ct) {
            bf8_t fw = *(const bf8_t*)(Wp1 + ((size_t)((ct * 4 + s) * 64 + lane)) * 8);
            #pragma unroll
            for (int rt = 0; rt < 2; ++rt)
                acc[rt][ct] = __builtin_amdgcn_mfma_f32_16x16x32_bf16(fa[rt], fw, acc[rt][ct], 0, 0, 0);
        }
    }

    // ---- per-lane BN fold (cols ct*16+m0): h1 = dot*S1 + T1 ; h2 = dot + T2 ----
    float S1r[8], T1r[8], T2r[8];
    #pragma unroll
    for (int ct = 0; ct < 8; ++ct) {
        int col = ct * 16 + m0;
        float b = b1[col];
        float g = bg[col], be = bb[col], m_ = bm[col], v_ = bv[col];
        float S = g * rsqrtf(v_ + 1e-5f);
        S1r[ct] = S;
        T1r[ct] = b * S + (be - m_ * S);
        T2r[ct] = b2[col];
    }

    // ---- epilogue 1: BN+ReLU, H -> sA (wave-own slab; in-order DS = RAW safe) ----
    // C/D layout: col = lane&15, row = (lane>>4)*4 + reg   [m89]
    #pragma unroll
    for (int rt = 0; rt < 2; ++rt) {
        #pragma unroll
        for (int r = 0; r < 4; ++r) {
            int rl = wv * 32 + rt * 16 + kq * 4 + r;
            #pragma unroll
            for (int ct = 0; ct < 8; ++ct) {
                int col = ct * 16 + m0;
                float v = acc[rt][ct][r] * S1r[ct] + T1r[ct];
                v = fmaxf(v, 0.f);
                int chunk = col >> 3;
                sA[rl * 128 + ((chunk ^ (rl & 7)) << 3) + (col & 7)] = (__bf16)v;
            }
        }
    }

    // ---- stage 2: H @ W2 ----
    f32x4 acc2[2][8];
    #pragma unroll
    for (int rt = 0; rt < 2; ++rt)
        #pragma unroll
        for (int ct = 0; ct < 8; ++ct) acc2[rt][ct] = (f32x4){0.f, 0.f, 0.f, 0.f};

    #pragma unroll
    for (int s = 0; s < 4; ++s) {
        bf8_t fa[2];
        #pragma unroll
        for (int rt = 0; rt < 2; ++rt) {
            int rl = wv * 32 + rt * 16 + m0;
            int chunk = s * 4 + kq;
            fa[rt] = *(const bf8_t*)&sA[rl * 128 + ((chunk ^ (rl & 7)) << 3)];
        }
        #pragma unroll
        for (int ct = 0; ct < 8; ++ct) {
            bf8_t fw = *(const bf8_t*)(Wp2 + ((size_t)((ct * 4 + s) * 64 + lane)) * 8);
            #pragma unroll
            for (int rt = 0; rt < 2; ++rt)
                acc2[rt][ct] = __builtin_amdgcn_mfma_f32_16x16x32_bf16(fa[rt], fw, acc2[rt][ct], 0, 0, 0);
        }
    }

    // ---- epilogue 2: + b2 (+ReLU), store bf16 ----
    #pragma unroll
    for (int rt = 0; rt < 2; ++rt) {
        #pragma unroll
        for (int r = 0; r < 4; ++r) {
            int row = rowBase + wv * 32 + rt * 16 + kq * 4 + r;
            if (row < M) {
                #pragma unroll
                for (int ct = 0; ct < 8; ++ct) {
                    int col = ct * 16 + m0;
                    float v = acc2[rt][ct][r] + T2r[ct];
                    if (RELU2) v = fmaxf(v, 0.f);
                    out[(size_t)row * 128 + col] = (__bf16)v;
                }
            }
        }
    }
}

// ---- plain fused GEMM (kept for the 128->64 output projection) ----
template<int NC, bool BN, bool RELU, bool OUTF32>
__launch_bounds__(256, 2)
__global__ void k_gemm(const __bf16* __restrict__ A, int M,
                       const float* __restrict__ W,
                       const float* __restrict__ bias,
                       const float* __restrict__ bg, const float* __restrict__ bb,
                       const float* __restrict__ bm, const float* __restrict__ bv,
                       void* __restrict__ outp) {
    constexpr int NT = NC / 16;
    __shared__ __bf16 sW[128 * NC];
    __shared__ float sS[NC];
    __shared__ float sT[NC];

    const float4* W4 = (const float4*)W;
    for (int e = threadIdx.x; e < 32 * NC; e += 256) {
        float4 w = W4[e];
        unsigned flat = (unsigned)e * 4;
        unsigned k = flat / NC, n = flat % NC;
        unsigned c = n >> 4, s = k >> 5, hi = (k >> 3) & 3, j = k & 7;
        unsigned l0 = (hi << 4) | (n & 15);
        unsigned base = ((c * 4 + s) * 64 + l0) * 8 + j;
        sW[base]      = (__bf16)w.x;
        sW[base + 8]  = (__bf16)w.y;
        sW[base + 16] = (__bf16)w.z;
        sW[base + 24] = (__bf16)w.w;
    }
    for (int n = threadIdx.x; n < NC; n += 256) {
        float b = bias[n];
        float S = 1.0f, T = b;
        if (BN) {
            float g = bg[n], be = bb[n], m = bm[n], v = bv[n];
            S = g * rsqrtf(v + 1e-5f);
            T = b * S + (be - m * S);
        }
        sS[n] = S; sT[n] = T;
    }
    __syncthreads();

    const int lane = threadIdx.x & 63;
    const int wv   = threadIdx.x >> 6;
    const int rowBase = blockIdx.x * 256 + wv * 64;
    const int m0 = lane & 15, kq = lane >> 4;

    f32x4 acc[4][NT];
    #pragma unroll
    for (int rt = 0; rt < 4; ++rt)
        #pragma unroll
        for (int ct = 0; ct < NT; ++ct)
            acc[rt][ct] = (f32x4){0.f, 0.f, 0.f, 0.f};

    #pragma unroll
    for (int s = 0; s < 4; ++s) {
        bf8_t fa[4];
        #pragma unroll
        for (int rt = 0; rt < 4; ++rt) {
            int r = rowBase + rt * 16 + m0;
            r = r < M ? r : M - 1;
            fa[rt] = *(const bf8_t*)(A + (size_t)r * 128 + s * 32 + kq * 8);
        }
        #pragma unroll
        for (int ct = 0; ct < NT; ++ct) {
            bf8_t fw = *(const bf8_t*)&sW[((ct * 4 + s) * 64 + lane) * 8];
            #pragma unroll
            for (int rt = 0; rt < 4; ++rt)
                acc[rt][ct] = __builtin_amdgcn_mfma_f32_16x16x32_bf16(fa[rt], fw, acc[rt][ct], 0, 0, 0);
        }
    }

    #pragma unroll
    for (int rt = 0; rt < 4; ++rt) {
        #pragma unroll
        for (int r = 0; r < 4; ++r) {
            int row = rowBase + rt * 16 + kq * 4 + r;
            if (row < M) {
                #pragma unroll
                for (int ct = 0; ct < NT; ++ct) {
                    int col = ct * 16 + m0;
                    float v = acc[rt][ct][r] * sS[col] + sT[col];
                    if (RELU) v = fmaxf(v, 0.0f);
                    size_t o = (size_t)row * NC + col;
                    if constexpr (OUTF32) ((float*)outp)[o]  = v;
                    else                  ((__bf16*)outp)[o] = (__bf16)v;
                }
            }
        }
    }
}

extern "C" void kernel_launch(void* const* d_in, const int* in_sizes, int n_in,
                              void* d_out, int out_size, void* d_ws, size_t ws_size,
                              hipStream_t stream) {
    const int*   edge_index = (const int*)d_in[0];     // [2, E_LINE]
    const float* x_orig     = (const float*)d_in[1];   // [N_NODES, 128] f32
    const int*   eio        = (const int*)d_in[2];     // [2, E_ORIG]
    const int*   pairs      = (const int*)d_in[3];     // [E_ORIG, 2]
    const float* iW1 = (const float*)d_in[4];
    const float* ib1 = (const float*)d_in[5];
    const float* ig  = (const float*)d_in[6];
    const float* ibb = (const float*)d_in[7];
    const float* im  = (const float*)d_in[8];
    const float* iv  = (const float*)d_in[9];
    const float* iW2 = (const float*)d_in[10];
    const float* ib2 = (const float*)d_in[11];
    const float* gW1 = (const float*)d_in[12];
    const float* gb1 = (const float*)d_in[13];
    const float* gg  = (const float*)d_in[14];
    const float* gbb = (const float*)d_in[15];
    const float* gm  = (const float*)d_in[16];
    const float* gv  = (const float*)d_in[17];
    const float* gW2 = (const float*)d_in[18];
    const float* gb2 = (const float*)d_in[19];
    const float* mW1 = (const float*)d_in[20];
    const float* mb1 = (const float*)d_in[21];
    const float* mg  = (const float*)d_in[22];
    const float* mbb = (const float*)d_in[23];
    const float* mm  = (const float*)d_in[24];
    const float* mv  = (const float*)d_in[25];
    const float* mW2 = (const float*)d_in[26];
    const float* mb2 = (const float*)d_in[27];
    const float* oW  = (const float*)d_in[28];
    const float* ob  = (const float*)d_in[29];

    // ---- workspace carve ----
    char* w = (char*)d_ws;
    __bf16* EB  = (__bf16*)w;                w += (size_t)E_ORIG * 128 * 2;   // 153.6 MB
    __bf16* XB  = (__bf16*)w;                w += (size_t)N_NODES * 128 * 2;  // 25.6 MB
    __bf16* NA  = (__bf16*)w;                w += (size_t)N_NODES * 128 * 2;  // 25.6 MB
    __bf16* NB  = (__bf16*)w;                w += (size_t)N_NODES * 128 * 2;  // 25.6 MB
    int* cnt  = (int*)w;                     w += (size_t)E_ORIG * 4;         // 2.4 MB
    int* offs = (int*)w;                     w += (size_t)E_ORIG * 4;         // 2.4 MB
    int* cur  = (int*)w;                     w += (size_t)E_ORIG * 4;         // 2.4 MB
    int* bsum = (int*)w;                     w += 4096 * 4;
    int* adj  = (int*)w;                     w += (size_t)E_LINE * 4;         // 4.8 MB
    __bf16* Wpk = (__bf16*)w;                /* 10 * 16384 bf16 = 320 KB */
    __bf16* EBd = (__bf16*)d_out;            // d_out doubles as edge scratch (bf16)

    const int* eio_src = eio;
    const int* eio_dst = eio + E_ORIG;
    const int* el_src  = edge_index;
    const int* el_dst  = edge_index + E_LINE;

    const int nBlk = cdiv(N_NODES, 128);       // 782
    const int eBlk = cdiv(E_ORIG, 128);        // 4688
    const int nScanNB = cdiv(N_NODES, 256);    // 391
    const int eScanNB = cdiv(E_ORIG, 256);     // 2344

    // ---- pre-pack all 128x128 weights to bf16 fragment-major (once per launch) ----
    WPtrs wp;
    wp.p[0] = iW1;          wp.p[1] = iW2;
    wp.p[2] = iW1 + 16384;  wp.p[3] = iW2 + 16384;
    wp.p[4] = mW1;          wp.p[5] = mW2;
    wp.p[6] = gW1;          wp.p[7] = gW2;
    wp.p[8] = gW1 + 16384;  wp.p[9] = gW2 + 16384;
    k_packW<<<10, 256, 0, stream>>>(wp, Wpk);

    // ==== node-graph CSR (dst = eio_dst, n = N_NODES, E = E_ORIG) ====
    hipMemsetAsync(cnt, 0, (size_t)N_NODES * 4, stream);
    k_hist <<<cdiv(E_ORIG, 256), 256, 0, stream>>>(eio_dst, cnt, E_ORIG);
    k_scan1<<<nScanNB, 256, 0, stream>>>(cnt, offs, bsum, N_NODES);
    k_scan2<<<1, 256, 0, stream>>>(bsum, nScanNB);
    k_scan3<<<nScanNB, 256, 0, stream>>>(offs, cur, bsum, N_NODES);
    k_fill <<<cdiv(E_ORIG, 256), 256, 0, stream>>>(eio_src, eio_dst, cur, adj, E_ORIG);

    // ==== node stage ====
    k_f2b<<<cdiv(N_NODES * 16, 256), 256, 0, stream>>>(x_orig, XB, N_NODES * 16);
    // init GIN layer 0 (fused agg + W1 + BN + ReLU + W2 + ReLU)
    k_layer<A_AGG, true><<<nBlk, 256, 0, stream>>>(XB, N_NODES, offs, cnt, adj, nullptr,
        Wpk + 0 * 16384, Wpk + 1 * 16384, ib1, ig, ibb, im, iv, ib2, NA);
    // init GIN layer 1
    k_layer<A_AGG, true><<<nBlk, 256, 0, stream>>>(NA, N_NODES, offs, cnt, adj, nullptr,
        Wpk + 2 * 16384, Wpk + 3 * 16384, ib1 + 128, ig + 128, ibb + 128, im + 128, iv + 128, ib2 + 128, NB);
    // per-node MLP (dense fused pair; plain second layer)
    k_layer<A_DENSE, false><<<nBlk, 256, 0, stream>>>(NB, N_NODES, nullptr, nullptr, nullptr, nullptr,
        Wpk + 4 * 16384, Wpk + 5 * 16384, mb1, mg, mbb, mm, mv, mb2, XB);

    // ==== line-graph CSR (dst = el_dst, n = E_ORIG, E = E_LINE) ====
    hipMemsetAsync(cnt, 0, (size_t)E_ORIG * 4, stream);
    k_hist <<<cdiv(E_LINE, 256), 256, 0, stream>>>(el_dst, cnt, E_LINE);
    k_scan1<<<eScanNB, 256, 0, stream>>>(cnt, offs, bsum, E_ORIG);
    k_scan2<<<1, 256, 0, stream>>>(bsum, eScanNB);
    k_scan3<<<eScanNB, 256, 0, stream>>>(offs, cur, bsum, E_ORIG);
    k_fill <<<cdiv(E_LINE, 256), 256, 0, stream>>>(el_src, el_dst, cur, adj, E_LINE);

    // ==== edge stage ====
    // GIN layer 0: pair-gather + agg + both GEMMs fused (EB / h never materialized)
    k_layer<A_PAIR, true><<<eBlk, 256, 0, stream>>>(XB, E_ORIG, offs, cnt, adj, pairs,
        Wpk + 6 * 16384, Wpk + 7 * 16384, gb1, gg, gbb, gm, gv, gb2, EBd);
    // GIN layer 1
    k_layer<A_AGG, true><<<eBlk, 256, 0, stream>>>(EBd, E_ORIG, offs, cnt, adj, nullptr,
        Wpk + 8 * 16384, Wpk + 9 * 16384, gb1 + 128, gg + 128, gbb + 128, gm + 128, gv + 128, gb2 + 128, EB);

    // ==== output projection: [E_ORIG,128]bf16 @ [128,64] + b -> d_out f32 ====
    k_gemm<64, false, false, true><<<cdiv(E_ORIG, 256), 256, 0, stream>>>(EB, E_ORIG, oW, ob,
        nullptr, nullptr, nullptr, nullptr, d_out);
}